// Round 2
// baseline (36827.332 us; speedup 1.0000x reference)
//
#include <hip/hip_runtime.h>
#include <cstddef>

#define HID   256
#define CTXD  128
#define QDIM  128
#define VDNUM 33
#define NBLK  256
#define NTHR  512

__device__ __forceinline__ float sigf(float x) { return 1.f / (1.f + expf(-x)); }

struct P {
    const int*   seqs;
    const float* key; const float* val; const float* embed;
    const float* Wih0; const float* Whh0; const float* bih0; const float* bhh0;
    const float* Wih1; const float* Whh1; const float* bih1; const float* bhh1;
    const float* Wih2; const float* Whh2; const float* bih2; const float* bhh2;
    const float* Wq;  const float* bq;
    const float* Ws1; const float* bs1;
    const float* Ws2; const float* bs2;
    float* hA; float* hB; float* cT; float* ctxT; float* energy;
    int* chr; unsigned* cnt; unsigned* gen;
    float* outS; float* outP;
    int S, T;
};

// ---------------------------------------------------------------------------
// Grid barrier: sense-free monotone generation counter. ACQ_REL arrival RMW
// publishes this block's phase writes (L2 writeback at agent scope); acquire
// on exit invalidates stale L1/L2 lines. Co-residency: 256 blocks on 256 CUs.
// ---------------------------------------------------------------------------
__device__ __forceinline__ void gridbar(const P& p, unsigned& g) {
    __syncthreads();
    if (threadIdx.x == 0) {
        unsigned old = __hip_atomic_fetch_add(p.cnt, 1u, __ATOMIC_ACQ_REL,
                                              __HIP_MEMORY_SCOPE_AGENT);
        if (old == NBLK - 1) {
            __hip_atomic_store(p.cnt, 0u, __ATOMIC_RELAXED, __HIP_MEMORY_SCOPE_AGENT);
            __hip_atomic_store(p.gen, g + 1u, __ATOMIC_RELEASE, __HIP_MEMORY_SCOPE_AGENT);
        } else {
            while (__hip_atomic_load(p.gen, __ATOMIC_RELAXED, __HIP_MEMORY_SCOPE_AGENT) <= g)
                __builtin_amdgcn_s_sleep(2);
            unsigned tmp = __hip_atomic_load(p.gen, __ATOMIC_ACQUIRE, __HIP_MEMORY_SCOPE_AGENT);
            (void)tmp;
        }
    }
    ++g;
    __syncthreads();
}

// ---------------------------------------------------------------------------
// LSTM layer phase. block = hidden unit j (256 blocks), threads:
// b = tid&63, gate = (tid>>6)&3, half = tid>>8 (0: input part, 1: recurrent).
// ---------------------------------------------------------------------------
template<int LAYER>
__device__ __forceinline__ void lstm_phase(const P& p, char* smraw,
    const float* xT, const float* hR, float* hW, float* cT)
{
    float (*g)[4][64] = reinterpret_cast<float(*)[4][64]>(smraw);  // [2][4][64]
    const int tid  = threadIdx.x;
    const int b    = tid & 63, gate = (tid >> 6) & 3, half = tid >> 8;
    const int j    = blockIdx.x;
    const int row  = (gate << 8) + j;   // torch gate order i,f,g,o

    const float* Wih = LAYER == 0 ? p.Wih0 : LAYER == 1 ? p.Wih1 : p.Wih2;
    const float* Whh = LAYER == 0 ? p.Whh0 : LAYER == 1 ? p.Whh1 : p.Whh2;
    const float* bih = LAYER == 0 ? p.bih0 : LAYER == 1 ? p.bih1 : p.bih2;
    const float* bhh = LAYER == 0 ? p.bhh0 : LAYER == 1 ? p.bhh1 : p.bhh2;

    float acc;
    if (half == 0) {
        acc = bih[row] + bhh[row];
        if (LAYER == 0) {
            const float* wi  = Wih + (size_t)row * (HID + CTXD);
            const float* emb = p.embed + p.chr[b] * HID;
            #pragma unroll 8
            for (int k = 0; k < HID; ++k)  acc += emb[k] * wi[k];
            #pragma unroll 8
            for (int k = 0; k < CTXD; ++k) acc += p.ctxT[k * 64 + b] * wi[HID + k];
        } else {
            const float* wi = Wih + (size_t)row * HID;
            #pragma unroll 8
            for (int k = 0; k < HID; ++k)  acc += xT[k * 64 + b] * wi[k];
        }
    } else {
        const float* wh = Whh + (size_t)row * HID;
        acc = 0.f;
        #pragma unroll 8
        for (int k = 0; k < HID; ++k)      acc += hR[k * 64 + b] * wh[k];
    }
    g[half][gate][b] = acc;
    __syncthreads();

    if (tid < 64) {
        float gi = g[0][0][tid] + g[1][0][tid];
        float gf = g[0][1][tid] + g[1][1][tid];
        float gg = g[0][2][tid] + g[1][2][tid];
        float go = g[0][3][tid] + g[1][3][tid];
        float cold = cT[j * 64 + tid];
        float cnew = sigf(gf) * cold + sigf(gi) * tanhf(gg);
        cT[j * 64 + tid] = cnew;
        hW[j * 64 + tid] = sigf(go) * tanhf(cnew);
    }
}

// ---------------------------------------------------------------------------
// Energy phase: 4 blocks per batch element (b = bid>>2, t-quarter = bid&3).
// Query computed redundantly per block (33k MACs, trivial). Thread =
// t4-in-chunk (128) x q-group (4x32) -> 32-deep load chains, LDS combine.
// ---------------------------------------------------------------------------
__device__ __forceinline__ void energy_phase(const P& p, char* smraw, const float* h2T)
{
    float* qry          = reinterpret_cast<float*>(smraw);               // [128]
    float (*qp)[QDIM]   = reinterpret_cast<float(*)[QDIM]>(smraw + 512); // [4][128]
    float4 (*ep)[128]   = reinterpret_cast<float4(*)[128]>(smraw + 2560);// [4][128]
    const int tid = threadIdx.x;
    const int b   = blockIdx.x >> 2, tq = blockIdx.x & 3;

    {   // query partials: 128 q x 4 k-quarters of 64
        const int q = tid & 127, kq = tid >> 7;
        const float* wq = p.Wq + (size_t)q * HID + kq * 64;
        const float* h2 = h2T + kq * 64 * 64;
        float a = 0.f;
        #pragma unroll 8
        for (int k = 0; k < 64; ++k) a += h2[k * 64 + b] * wq[k];
        qp[kq][q] = a;
    }
    __syncthreads();
    if (tid < QDIM)
        qry[tid] = p.bq[tid] + qp[0][tid] + qp[1][tid] + qp[2][tid] + qp[3][tid];
    __syncthreads();

    const int T4  = p.T >> 2;                 // 512
    const int t4l = tid & 127, qg = tid >> 7;
    const float4* key4 = (const float4*)p.key + (size_t)b * QDIM * T4
                       + (size_t)tq * 128 + t4l;
    float4 e = make_float4(0.f, 0.f, 0.f, 0.f);
    const int q0 = qg * 32;
    #pragma unroll 4
    for (int qq = 0; qq < 32; ++qq) {
        float4 k4 = key4[(size_t)(q0 + qq) * T4];
        float  qv = qry[q0 + qq];
        e.x += qv * k4.x; e.y += qv * k4.y; e.z += qv * k4.z; e.w += qv * k4.w;
    }
    ep[qg][t4l] = e;
    __syncthreads();
    if (tid < 128) {
        float4 r0 = ep[0][tid], r1 = ep[1][tid], r2 = ep[2][tid], r3 = ep[3][tid];
        float4 r;
        r.x = ((r0.x + r1.x) + r2.x) + r3.x;
        r.y = ((r0.y + r1.y) + r2.y) + r3.y;
        r.z = ((r0.z + r1.z) + r2.z) + r3.z;
        r.w = ((r0.w + r1.w) + r2.w) + r3.w;
        ((float4*)p.energy)[(size_t)b * T4 + tq * 128 + tid] = r;
    }
}

// ---------------------------------------------------------------------------
// Attention tail: blocks 0..63 (b = bid). Exact round-0 numerics: global max
// softmax -> mask -> renorm(1e-12) -> scores out -> ctx (bounded n) -> MLP ->
// predict out -> argmax feedback.
// ---------------------------------------------------------------------------
__device__ __forceinline__ void attn_phase(const P& p, char* smraw, const float* h2T, int s)
{
    float*  s_lds  = reinterpret_cast<float*>(smraw);                 // [2048]
    float4 (*red)[32] = reinterpret_cast<float4(*)[32]>(smraw + 8192);// [16][32]
    float*  ctxl   = reinterpret_cast<float*>(smraw + 16384);         // [128]
    float*  hid    = reinterpret_cast<float*>(smraw + 16896);         // [256]
    float*  predv  = reinterpret_cast<float*>(smraw + 17920);         // [33]
    float*  wred   = reinterpret_cast<float*>(smraw + 18052);         // [8]
    float*  bc     = reinterpret_cast<float*>(smraw + 18084);         // [1]

    const int tid = threadIdx.x;
    const int b   = blockIdx.x;
    const int T   = p.T;

    float m = -INFINITY;
    for (int t = tid; t < T; t += NTHR) {
        float v = p.energy[(size_t)b * T + t];
        s_lds[t] = v;
        m = fmaxf(m, v);
    }
    #pragma unroll
    for (int off = 32; off; off >>= 1) m = fmaxf(m, __shfl_xor(m, off));
    if ((tid & 63) == 0) wred[tid >> 6] = m;
    __syncthreads();
    if (tid == 0) { float r = wred[0]; for (int i = 1; i < 8; ++i) r = fmaxf(r, wred[i]); *bc = r; }
    __syncthreads();
    m = *bc;

    float zs = 0.f;
    for (int t = tid; t < T; t += NTHR) { float pp = expf(s_lds[t] - m); s_lds[t] = pp; zs += pp; }
    #pragma unroll
    for (int off = 32; off; off >>= 1) zs += __shfl_xor(zs, off);
    __syncthreads();
    if ((tid & 63) == 0) wred[tid >> 6] = zs;
    __syncthreads();
    if (tid == 0) { float r = 0.f; for (int i = 0; i < 8; ++i) r += wred[i]; *bc = r; }
    __syncthreads();
    const float Z = *bc;

    const int n = p.seqs[b];
    float ms = 0.f;
    for (int t = tid; t < T; t += NTHR) {
        float sc = s_lds[t] / Z;
        sc = (t < n) ? sc : 0.f;
        s_lds[t] = sc;
        ms += sc;
    }
    #pragma unroll
    for (int off = 32; off; off >>= 1) ms += __shfl_xor(ms, off);
    __syncthreads();
    if ((tid & 63) == 0) wred[tid >> 6] = ms;
    __syncthreads();
    if (tid == 0) { float r = 0.f; for (int i = 0; i < 8; ++i) r += wred[i]; *bc = r; }
    __syncthreads();
    const float denom = fmaxf(*bc, 1e-12f);

    float* so = p.outS + (size_t)b * ((size_t)p.S * T) + (size_t)s * T;
    for (int t = tid; t < T; t += NTHR) {
        float sc = s_lds[t] / denom;
        s_lds[t] = sc;
        so[t]    = sc;
    }
    __syncthreads();

    // ctx
    const int c4 = tid & 31, grp = tid >> 5;
    const float4* val4 = (const float4*)p.val + (size_t)b * T * 32;
    float4 a4 = make_float4(0.f, 0.f, 0.f, 0.f);
    #pragma unroll 4
    for (int t = grp; t < n; t += 16) {
        float  sv = s_lds[t];
        float4 v4 = val4[(size_t)t * 32 + c4];
        a4.x += sv * v4.x; a4.y += sv * v4.y; a4.z += sv * v4.z; a4.w += sv * v4.w;
    }
    red[grp][c4] = a4;
    __syncthreads();
    if (tid < 32) {
        float4 r = red[0][tid];
        for (int g2 = 1; g2 < 16; ++g2) {
            float4 q = red[g2][tid];
            r.x += q.x; r.y += q.y; r.z += q.z; r.w += q.w;
        }
        const int c0 = tid * 4;
        ctxl[c0 + 0] = r.x; ctxl[c0 + 1] = r.y; ctxl[c0 + 2] = r.z; ctxl[c0 + 3] = r.w;
        p.ctxT[(c0 + 0) * 64 + b] = r.x;
        p.ctxT[(c0 + 1) * 64 + b] = r.y;
        p.ctxT[(c0 + 2) * 64 + b] = r.z;
        p.ctxT[(c0 + 3) * 64 + b] = r.w;
    }
    __syncthreads();

    // MLP
    if (tid < HID) {
        float a = p.bs1[tid];
        const float* w1 = p.Ws1 + (size_t)tid * (HID + CTXD);
        #pragma unroll 8
        for (int k = 0; k < HID; ++k)  a += h2T[k * 64 + b] * w1[k];
        #pragma unroll 8
        for (int k = 0; k < CTXD; ++k) a += ctxl[k] * w1[HID + k];
        hid[tid] = fmaxf(a, 0.f);
    }
    __syncthreads();
    if (tid < VDNUM) {
        float a = p.bs2[tid];
        const float* w2 = p.Ws2 + (size_t)tid * HID;
        #pragma unroll 8
        for (int k = 0; k < HID; ++k) a += hid[k] * w2[k];
        p.outP[(size_t)b * p.S * VDNUM + (size_t)s * VDNUM + tid] = a;
        predv[tid] = a;
    }
    __syncthreads();
    if (tid == 0) {  // first-occurrence argmax (strict >)
        int best = 0; float bv = predv[0];
        for (int v = 1; v < VDNUM; ++v) if (predv[v] > bv) { bv = predv[v]; best = v; }
        p.chr[b] = best;
    }
}

// ---------------------------------------------------------------------------
// Persistent kernel: whole 220-step loop, 5 grid barriers per step.
// ---------------------------------------------------------------------------
__global__ __launch_bounds__(NTHR) void speller(P p)
{
    __shared__ __align__(16) char smraw[18432];
    unsigned g = 0;
    for (int s = 0; s < p.S; ++s) {
        const float* hR = (s & 1) ? p.hB : p.hA;
        float*       hW = (s & 1) ? p.hA : p.hB;

        lstm_phase<0>(p, smraw, nullptr,     hR,         hW,         p.cT);
        gridbar(p, g);
        lstm_phase<1>(p, smraw, hW,          hR + 16384, hW + 16384, p.cT + 16384);
        gridbar(p, g);
        lstm_phase<2>(p, smraw, hW + 16384,  hR + 32768, hW + 32768, p.cT + 32768);
        gridbar(p, g);
        energy_phase(p, smraw, hW + 32768);
        gridbar(p, g);
        if (blockIdx.x < 64) attn_phase(p, smraw, hW + 32768, s);
        gridbar(p, g);
    }
}

__global__ void init_kernel(P p, const float* h0, const float* c0, const float* con)
{
    int i = blockIdx.x * NTHR + threadIdx.x;    // 96*512 = 49152 threads
    if (i < 3 * HID * 64) { p.hA[i] = h0[i >> 6]; p.cT[i] = c0[i >> 6]; }
    if (i < CTXD * 64)      p.ctxT[i] = con[i >> 6];
    if (i < 64)             p.chr[i]  = 0;
    if (i == 0)             { *p.cnt = 0u; *p.gen = 0u; }
}

extern "C" void kernel_launch(void* const* d_in, const int* in_sizes, int n_in,
                              void* d_out, int out_size, void* d_ws, size_t ws_size,
                              hipStream_t stream)
{
    P p;
    p.seqs  = (const int*)  d_in[0];
    p.key   = (const float*)d_in[1];
    p.val   = (const float*)d_in[2];
    p.embed = (const float*)d_in[4];
    p.Wih0  = (const float*)d_in[5];  p.Whh0 = (const float*)d_in[6];
    p.bih0  = (const float*)d_in[7];  p.bhh0 = (const float*)d_in[8];
    p.Wih1  = (const float*)d_in[9];  p.Whh1 = (const float*)d_in[10];
    p.bih1  = (const float*)d_in[11]; p.bhh1 = (const float*)d_in[12];
    p.Wih2  = (const float*)d_in[13]; p.Whh2 = (const float*)d_in[14];
    p.bih2  = (const float*)d_in[15]; p.bhh2 = (const float*)d_in[16];
    p.Wq    = (const float*)d_in[17]; p.bq   = (const float*)d_in[18];
    p.Ws1   = (const float*)d_in[19]; p.bs1  = (const float*)d_in[20];
    p.Ws2   = (const float*)d_in[21]; p.bs2  = (const float*)d_in[22];
    const float* h0  = (const float*)d_in[23];
    const float* c0  = (const float*)d_in[24];
    const float* con = (const float*)d_in[25];

    const int B = in_sizes[0];                  // 64
    p.T = in_sizes[1] / (B * QDIM);             // 2048
    p.S = in_sizes[3] / B;                      // 220

    float* ws = (float*)d_ws;
    p.hA     = ws;
    p.hB     = ws + 49152;
    p.cT     = ws + 98304;
    p.ctxT   = ws + 147456;
    p.energy = ws + 155648;                     // 131072 floats
    p.chr    = (int*)(ws + 286720);
    p.cnt    = (unsigned*)(p.chr + 64);
    p.gen    = p.cnt + 1;

    p.outS = (float*)d_out;
    p.outP = p.outS + (size_t)B * p.S * p.T;

    init_kernel<<<96, NTHR, 0, stream>>>(p, h0, c0, con);
    speller<<<NBLK, NTHR, 0, stream>>>(p);
}

// Round 3
// 27623.425 us; speedup vs baseline: 1.3332x; 1.3332x over previous
//
#include <hip/hip_runtime.h>
#include <cstddef>

#define HID   256
#define CTXD  128
#define QDIM  128
#define VDNUM 33
#define NBLK  256
#define NTHR  512
#define GRPS  8

__device__ __forceinline__ float sigf(float x) { return 1.f / (1.f + expf(-x)); }

struct P {
    const int*   seqs;
    const float* key; const float* val; const float* embed;
    const float* Wih0; const float* Whh0; const float* bih0; const float* bhh0;
    const float* Wih1; const float* Whh1; const float* bih1; const float* bhh1;
    const float* Wih2; const float* Whh2; const float* bih2; const float* bhh2;
    const float* Wq;  const float* bq;
    const float* Ws1; const float* bs1;
    const float* Ws2; const float* bs2;
    float* hA; float* hB; float* cT; float* ctxT; float* energy;
    float* pm; float* pz; float* cp;
    int* chr; unsigned* cnt;   // cnt[0..127] group counters (16 apart), [128]=master, [129]=gen
    float* outS; float* outP;
    int S, T;
};

// ---------------------------------------------------------------------------
// Two-level grid barrier: 8 spread sub-counters (64B apart) -> master -> gen.
// ACQ_REL chain gives transitive happens-before; resets ordered before the
// RELEASE gen store; spinners ACQUIRE gen. 256 blocks co-resident on 256 CUs.
// ---------------------------------------------------------------------------
__device__ __forceinline__ void gridbar(const P& p, unsigned& g) {
    __syncthreads();
    if (threadIdx.x == 0) {
        unsigned* gen = p.cnt + 128 + 1;
        unsigned* mst = p.cnt + 128;
        unsigned* c   = p.cnt + (blockIdx.x & (GRPS - 1)) * 16;
        bool last = false;
        unsigned old = __hip_atomic_fetch_add(c, 1u, __ATOMIC_ACQ_REL, __HIP_MEMORY_SCOPE_AGENT);
        if (old == NBLK / GRPS - 1) {
            unsigned o2 = __hip_atomic_fetch_add(mst, 1u, __ATOMIC_ACQ_REL, __HIP_MEMORY_SCOPE_AGENT);
            if (o2 == GRPS - 1) {
                #pragma unroll
                for (int i = 0; i < GRPS; ++i)
                    __hip_atomic_store(p.cnt + i * 16, 0u, __ATOMIC_RELAXED, __HIP_MEMORY_SCOPE_AGENT);
                __hip_atomic_store(mst, 0u, __ATOMIC_RELAXED, __HIP_MEMORY_SCOPE_AGENT);
                __hip_atomic_store(gen, g + 1u, __ATOMIC_RELEASE, __HIP_MEMORY_SCOPE_AGENT);
                last = true;
            }
        }
        if (!last) {
            while (__hip_atomic_load(gen, __ATOMIC_RELAXED, __HIP_MEMORY_SCOPE_AGENT) <= g)
                __builtin_amdgcn_s_sleep(2);
            (void)__hip_atomic_load(gen, __ATOMIC_ACQUIRE, __HIP_MEMORY_SCOPE_AGENT);
        }
    }
    ++g;
    __syncthreads();
}

// ---------------------------------------------------------------------------
// LSTM layer. block = hidden unit j, thread = (half, gate, b). Weight rows are
// wave-uniform -> readfirstlane pins them to SGPR-based s_load streams.
// ---------------------------------------------------------------------------
template<int LAYER>
__device__ __forceinline__ void lstm_phase(const P& p, char* smraw,
    const float* xT, const float* hR, float* hW, float* cT)
{
    float (*g)[4][64] = reinterpret_cast<float(*)[4][64]>(smraw);
    const int tid  = threadIdx.x;
    const int b    = tid & 63, gate = (tid >> 6) & 3, half = tid >> 8;
    const int j    = blockIdx.x;
    const int row  = __builtin_amdgcn_readfirstlane((gate << 8) + j);

    const float* Wih = LAYER == 0 ? p.Wih0 : LAYER == 1 ? p.Wih1 : p.Wih2;
    const float* Whh = LAYER == 0 ? p.Whh0 : LAYER == 1 ? p.Whh1 : p.Whh2;
    const float* bih = LAYER == 0 ? p.bih0 : LAYER == 1 ? p.bih1 : p.bih2;
    const float* bhh = LAYER == 0 ? p.bhh0 : LAYER == 1 ? p.bhh1 : p.bhh2;

    float acc;
    if (half == 0) {
        acc = bih[row] + bhh[row];
        if (LAYER == 0) {
            const float* wi  = Wih + (size_t)row * (HID + CTXD);
            const float* emb = p.embed + p.chr[b] * HID;
            #pragma unroll 8
            for (int k = 0; k < HID; ++k)  acc += emb[k] * wi[k];
            #pragma unroll 8
            for (int k = 0; k < CTXD; ++k) acc += p.ctxT[k * 64 + b] * wi[HID + k];
        } else {
            const float* wi = Wih + (size_t)row * HID;
            #pragma unroll 8
            for (int k = 0; k < HID; ++k)  acc += xT[k * 64 + b] * wi[k];
        }
    } else {
        const float* wh = Whh + (size_t)row * HID;
        acc = 0.f;
        #pragma unroll 8
        for (int k = 0; k < HID; ++k)      acc += hR[k * 64 + b] * wh[k];
    }
    g[half][gate][b] = acc;
    __syncthreads();

    if (tid < 64) {
        float gi = g[0][0][tid] + g[1][0][tid];
        float gf = g[0][1][tid] + g[1][1][tid];
        float gg = g[0][2][tid] + g[1][2][tid];
        float go = g[0][3][tid] + g[1][3][tid];
        float cold = cT[j * 64 + tid];
        float cnew = sigf(gf) * cold + sigf(gi) * tanhf(gg);
        cT[j * 64 + tid] = cnew;
        hW[j * 64 + tid] = sigf(go) * tanhf(cnew);
    }
}

// ---------------------------------------------------------------------------
// Phase D: energy for t<n in this block's T-quarter + partial (max, expsum).
// 256 blocks: b = bid>>2, quarter tq = bid&3. Query computed redundantly.
// ---------------------------------------------------------------------------
__device__ __forceinline__ void energy_phase(const P& p, char* smraw, const float* h2T)
{
    float* qry        = reinterpret_cast<float*>(smraw);                 // 128
    float (*qp)[128]  = reinterpret_cast<float(*)[128]>(smraw + 512);    // 4x128
    float4 (*ep)[128] = reinterpret_cast<float4(*)[128]>(smraw + 2560);  // 4x128 f4
    float* wr         = reinterpret_cast<float*>(smraw + 2560 + 8192);   // 8

    const int tid = threadIdx.x;
    const int b   = blockIdx.x >> 2, tq = blockIdx.x & 3;
    const int n   = p.seqs[b];
    const int t0  = tq << 9;
    const bool active = t0 < n;
    const int vlim = n - t0;                       // valid t in quarter

    {   // query partials: 128 q x 4 k-quarters
        const int q = tid & 127, kq = tid >> 7;
        const float* wq = p.Wq + (size_t)q * HID + kq * 64;
        const float* h2 = h2T + kq * 64 * 64;
        float a = 0.f;
        #pragma unroll 8
        for (int k = 0; k < 64; ++k) a += h2[k * 64 + b] * wq[k];
        qp[kq][q] = a;
    }
    __syncthreads();
    if (tid < QDIM)
        qry[tid] = p.bq[tid] + qp[0][tid] + qp[1][tid] + qp[2][tid] + qp[3][tid];
    __syncthreads();

    const int T4  = p.T >> 2;
    const int t4l = tid & 127, qg = tid >> 7;
    if (active) {
        const float4* key4 = (const float4*)p.key + (size_t)b * QDIM * T4 + (t0 >> 2) + t4l;
        float4 e = make_float4(0.f, 0.f, 0.f, 0.f);
        const int q0 = qg * 32;
        #pragma unroll 4
        for (int qq = 0; qq < 32; ++qq) {
            float4 k4 = key4[(size_t)(q0 + qq) * T4];
            float  qv = qry[q0 + qq];
            e.x += qv * k4.x; e.y += qv * k4.y; e.z += qv * k4.z; e.w += qv * k4.w;
        }
        ep[qg][t4l] = e;
    }
    __syncthreads();

    float m = -INFINITY;
    float4 ec = make_float4(0.f, 0.f, 0.f, 0.f);
    if (active && tid < 128) {
        float4 r0 = ep[0][tid], r1 = ep[1][tid], r2 = ep[2][tid], r3 = ep[3][tid];
        ec.x = ((r0.x + r1.x) + r2.x) + r3.x;
        ec.y = ((r0.y + r1.y) + r2.y) + r3.y;
        ec.z = ((r0.z + r1.z) + r2.z) + r3.z;
        ec.w = ((r0.w + r1.w) + r2.w) + r3.w;
        ((float4*)(p.energy + (size_t)b * p.T + t0))[tid] = ec;
        const int lt = tid * 4;
        if (lt + 0 < vlim) m = fmaxf(m, ec.x);
        if (lt + 1 < vlim) m = fmaxf(m, ec.y);
        if (lt + 2 < vlim) m = fmaxf(m, ec.z);
        if (lt + 3 < vlim) m = fmaxf(m, ec.w);
    }
    #pragma unroll
    for (int off = 32; off; off >>= 1) m = fmaxf(m, __shfl_xor(m, off));
    if ((tid & 63) == 0) wr[tid >> 6] = m;
    __syncthreads();
    float mg = wr[0];
    #pragma unroll
    for (int i = 1; i < 8; ++i) mg = fmaxf(mg, wr[i]);
    __syncthreads();

    float z = 0.f;
    if (active && tid < 128) {
        const int lt = tid * 4;
        if (lt + 0 < vlim) z += expf(ec.x - mg);
        if (lt + 1 < vlim) z += expf(ec.y - mg);
        if (lt + 2 < vlim) z += expf(ec.z - mg);
        if (lt + 3 < vlim) z += expf(ec.w - mg);
    }
    #pragma unroll
    for (int off = 32; off; off >>= 1) z += __shfl_xor(z, off);
    if ((tid & 63) == 0) wr[tid >> 6] = z;
    __syncthreads();
    if (tid == 0) {
        float zg = 0.f;
        #pragma unroll
        for (int i = 0; i < 8; ++i) zg += wr[i];
        p.pm[b * 4 + tq] = active ? mg : -INFINITY;
        p.pz[b * 4 + tq] = zg;
    }
}

// ---------------------------------------------------------------------------
// Phase E: merge (m,Z) partials, write scores for this quarter (0 for t>=n),
// accumulate ctx partial over this quarter. 256 blocks.
// ---------------------------------------------------------------------------
__device__ __forceinline__ void score_ctx_phase(const P& p, char* smraw, int s)
{
    float* s_sc       = reinterpret_cast<float*>(smraw);                 // 512
    float4 (*red)[32] = reinterpret_cast<float4(*)[32]>(smraw + 2048);   // 16x32 f4

    const int tid = threadIdx.x;
    const int b   = blockIdx.x >> 2, tq = blockIdx.x & 3;
    const int n   = p.seqs[b];
    const int t0  = tq << 9;

    float m = -INFINITY;
    float pmv[4], pzv[4];
    #pragma unroll
    for (int i = 0; i < 4; ++i) {
        pmv[i] = p.pm[b * 4 + i];
        pzv[i] = p.pz[b * 4 + i];
        m = fmaxf(m, pmv[i]);
    }
    float Z = 0.f;
    #pragma unroll
    for (int i = 0; i < 4; ++i) Z += pzv[i] * expf(pmv[i] - m);   // -inf -> exp=0, pz=0

    const int t = t0 + tid;
    float sc = 0.f;
    if (t < n) sc = expf(p.energy[(size_t)b * p.T + t] - m) / Z;
    p.outS[(size_t)b * p.S * p.T + (size_t)s * p.T + t] = sc;
    s_sc[tid] = sc;
    __syncthreads();

    const int c4 = tid & 31, grp = tid >> 5;
    const float4* val4 = (const float4*)p.val + (size_t)b * p.T * 32;
    float4 a4 = make_float4(0.f, 0.f, 0.f, 0.f);
    const int tend = min(t0 + 512, n);
    #pragma unroll 4
    for (int tt = t0 + grp; tt < tend; tt += 16) {
        float  sv = s_sc[tt - t0];
        float4 v4 = val4[(size_t)tt * 32 + c4];
        a4.x += sv * v4.x; a4.y += sv * v4.y; a4.z += sv * v4.z; a4.w += sv * v4.w;
    }
    red[grp][c4] = a4;
    __syncthreads();
    if (tid < 32) {
        float4 r = red[0][tid];
        #pragma unroll
        for (int g2 = 1; g2 < 16; ++g2) {
            float4 q = red[g2][tid];
            r.x += q.x; r.y += q.y; r.z += q.z; r.w += q.w;
        }
        ((float4*)(p.cp + ((size_t)tq * 64 + b) * 128))[tid] = r;
    }
}

// ---------------------------------------------------------------------------
// Phase F: blocks 0..63 (b = bid). Reduce ctx partials -> ctxT, MLP, predict,
// argmax feedback. hid/predict staged in LDS.
// ---------------------------------------------------------------------------
__device__ __forceinline__ void mlp_phase(const P& p, char* smraw, const float* h2T, int s)
{
    float* ctxl  = reinterpret_cast<float*>(smraw);            // 128
    float* h2l   = ctxl + 128;                                 // 256
    float* hp    = h2l + 256;                                  // 2x256
    float* hidl  = hp + 512;                                   // 256
    float* pp    = hidl + 256;                                 // 33x8
    float* predv = pp + 264;                                   // 33

    const int tid = threadIdx.x;
    const int b   = blockIdx.x;

    if (tid < 128) {
        const float* c0 = p.cp + (size_t)b * 128;
        float v = c0[tid] + c0[64 * 128 + tid] + c0[128 * 128 + tid] + c0[192 * 128 + tid];
        ctxl[tid] = v;
        p.ctxT[tid * 64 + b] = v;
    } else if (tid < 384) {
        const int k = tid - 128;
        h2l[k] = h2T[k * 64 + b];
    }
    __syncthreads();

    {   // hid[j] split into two 192-length halves
        const int j = tid & 255, half = tid >> 8;
        const float* w1 = p.Ws1 + (size_t)j * (HID + CTXD) + half * 192;
        float a = 0.f;
        if (half == 0) {
            #pragma unroll 8
            for (int k = 0; k < 192; ++k) a += h2l[k] * w1[k];
        } else {
            #pragma unroll 8
            for (int k = 0; k < 192; ++k) {
                const int kk = 192 + k;
                float f = (kk < 256) ? h2l[kk] : ctxl[kk - 256];
                a += f * w1[k];
            }
        }
        hp[half * 256 + j] = a;
    }
    __syncthreads();
    if (tid < 256) hidl[tid] = fmaxf(p.bs1[tid] + hp[tid] + hp[256 + tid], 0.f);
    __syncthreads();

    if (tid < 264) {   // 33 logits x 8 k-octants of 32
        const int v = tid >> 3, oct = tid & 7;
        const float* w2 = p.Ws2 + (size_t)v * HID + oct * 32;
        float a = 0.f;
        #pragma unroll 8
        for (int k = 0; k < 32; ++k) a += hidl[oct * 32 + k] * w2[k];
        pp[v * 8 + oct] = a;
    }
    __syncthreads();
    if (tid < VDNUM) {
        float a = p.bs2[tid];
        #pragma unroll
        for (int o = 0; o < 8; ++o) a += pp[tid * 8 + o];
        p.outP[(size_t)b * p.S * VDNUM + (size_t)s * VDNUM + tid] = a;
        predv[tid] = a;
    }
    __syncthreads();
    if (tid == 0) {   // first-occurrence argmax (strict >)
        int best = 0; float bv = predv[0];
        for (int v = 1; v < VDNUM; ++v) if (predv[v] > bv) { bv = predv[v]; best = v; }
        p.chr[b] = best;
    }
}

// ---------------------------------------------------------------------------
// Persistent kernel: 220 steps x 6 grid barriers.
// ---------------------------------------------------------------------------
__global__ __launch_bounds__(NTHR) void speller(P p)
{
    __shared__ __align__(16) char smraw[12288];
    unsigned g = 0;
    for (int s = 0; s < p.S; ++s) {
        const float* hR = (s & 1) ? p.hB : p.hA;
        float*       hW = (s & 1) ? p.hA : p.hB;

        lstm_phase<0>(p, smraw, nullptr,     hR,         hW,         p.cT);
        gridbar(p, g);
        lstm_phase<1>(p, smraw, hW,          hR + 16384, hW + 16384, p.cT + 16384);
        gridbar(p, g);
        lstm_phase<2>(p, smraw, hW + 16384,  hR + 32768, hW + 32768, p.cT + 32768);
        gridbar(p, g);
        energy_phase(p, smraw, hW + 32768);
        gridbar(p, g);
        score_ctx_phase(p, smraw, s);
        gridbar(p, g);
        if (blockIdx.x < 64) mlp_phase(p, smraw, hW + 32768, s);
        gridbar(p, g);
    }
}

__global__ void init_kernel(P p, const float* h0, const float* c0, const float* con)
{
    int i = blockIdx.x * NTHR + threadIdx.x;
    if (i < 3 * HID * 64) { p.hA[i] = h0[i >> 6]; p.cT[i] = c0[i >> 6]; }
    if (i < CTXD * 64)      p.ctxT[i] = con[i >> 6];
    if (i < 64)             p.chr[i]  = 0;
    if (i < 192)            p.cnt[i]  = 0u;
}

extern "C" void kernel_launch(void* const* d_in, const int* in_sizes, int n_in,
                              void* d_out, int out_size, void* d_ws, size_t ws_size,
                              hipStream_t stream)
{
    P p;
    p.seqs  = (const int*)  d_in[0];
    p.key   = (const float*)d_in[1];
    p.val   = (const float*)d_in[2];
    p.embed = (const float*)d_in[4];
    p.Wih0  = (const float*)d_in[5];  p.Whh0 = (const float*)d_in[6];
    p.bih0  = (const float*)d_in[7];  p.bhh0 = (const float*)d_in[8];
    p.Wih1  = (const float*)d_in[9];  p.Whh1 = (const float*)d_in[10];
    p.bih1  = (const float*)d_in[11]; p.bhh1 = (const float*)d_in[12];
    p.Wih2  = (const float*)d_in[13]; p.Whh2 = (const float*)d_in[14];
    p.bih2  = (const float*)d_in[15]; p.bhh2 = (const float*)d_in[16];
    p.Wq    = (const float*)d_in[17]; p.bq   = (const float*)d_in[18];
    p.Ws1   = (const float*)d_in[19]; p.bs1  = (const float*)d_in[20];
    p.Ws2   = (const float*)d_in[21]; p.bs2  = (const float*)d_in[22];
    const float* h0  = (const float*)d_in[23];
    const float* c0  = (const float*)d_in[24];
    const float* con = (const float*)d_in[25];

    const int B = in_sizes[0];                  // 64
    p.T = in_sizes[1] / (B * QDIM);             // 2048
    p.S = in_sizes[3] / B;                      // 220

    float* ws = (float*)d_ws;
    p.hA     = ws;                              // 49152
    p.hB     = ws + 49152;
    p.cT     = ws + 98304;
    p.ctxT   = ws + 147456;                     // 8192
    p.energy = ws + 155648;                     // 131072
    p.pm     = ws + 286720;                     // 256
    p.pz     = ws + 286976;                     // 256
    p.cp     = ws + 287232;                     // 4*64*128 = 32768
    p.chr    = (int*)(ws + 320000);             // 64
    p.cnt    = (unsigned*)(ws + 320064);        // 192 (sub-counters/master/gen)

    p.outS = (float*)d_out;
    p.outP = p.outS + (size_t)B * p.S * p.T;

    init_kernel<<<96, NTHR, 0, stream>>>(p, h0, c0, con);
    speller<<<NBLK, NTHR, 0, stream>>>(p);
}